// Round 7
// baseline (245.591 us; speedup 1.0000x reference)
//
#include <hip/hip_runtime.h>
#include <hip/hip_bf16.h>
#include <stdint.h>

typedef unsigned short u16;
typedef uint32_t u32;
typedef __attribute__((ext_vector_type(4))) float f32x4;
typedef __attribute__((ext_vector_type(16))) float f32x16;
typedef __attribute__((ext_vector_type(8))) short s8v;     // 8 bf16 as shorts (4 VGPR)
typedef __attribute__((ext_vector_type(4))) unsigned short u16x4;
typedef __attribute__((ext_vector_type(2))) uint32_t u32x2;

#define SCALE_Q 0.18033688f   // (1/8) * log2(e): scores come out in log2 domain

union PU { s8v v; u32 w[4]; };

__device__ __forceinline__ u16 f2bf(float f) {
  union { float f; uint32_t u; } v; v.f = f;
  uint32_t r = v.u + 0x7fffu + ((v.u >> 16) & 1u);   // RNE, no NaN inputs
  return (u16)(r >> 16);
}

__device__ __forceinline__ u32 pk2(float lo, float hi) {
  __hip_bfloat162 h = __float22bfloat162_rn(float2{lo, hi});
  union { __hip_bfloat162 h; u32 u; } c; c.h = h; return c.u;
}

// async global->LDS, 16B per lane; LDS base is WAVE-UNIFORM (HW adds lane*16)
__device__ __forceinline__ void gl16(const void* g, void* l) {
  __builtin_amdgcn_global_load_lds((const __attribute__((address_space(1))) u32*)g,
                                   (__attribute__((address_space(3))) u32*)l, 16, 0, 0);
}

#define BARRIER()  __builtin_amdgcn_s_barrier()
#define SCHEDB()   __builtin_amdgcn_sched_barrier(0)

// ---------- activation f32->bf16 ----------
__global__ __launch_bounds__(256) void k_conv3(const float* __restrict__ a, const float* __restrict__ b,
                                               const float* __restrict__ c, u16* __restrict__ oa,
                                               u16* __restrict__ ob, u16* __restrict__ oc) {
  int which = blockIdx.y;
  const float* in = which == 0 ? a : (which == 1 ? b : c);
  u16* out = which == 0 ? oa : (which == 1 ? ob : oc);
  int i = (blockIdx.x * 256 + threadIdx.x) * 4;
  float4 v = *(const float4*)(in + i);
  u16x4 o; o[0] = f2bf(v.x); o[1] = f2bf(v.y); o[2] = f2bf(v.z); o[3] = f2bf(v.w);
  *(u16x4*)(out + i) = o;
}

// W[h][d][kk] f32 -> WT[n=h*64+kk][d] bf16 (LDS-tiled transpose)
__global__ __launch_bounds__(256) void k_convW_t(const float* __restrict__ wq, const float* __restrict__ wk,
                                                 const float* __restrict__ wv, u16* __restrict__ oq,
                                                 u16* __restrict__ ok, u16* __restrict__ ov) {
  __shared__ float T[64][65];
  const int z = blockIdx.z, h = blockIdx.y, d0 = blockIdx.x * 64;
  const float* w = z == 0 ? wq : (z == 1 ? wk : wv);
  u16* o = z == 0 ? oq : (z == 1 ? ok : ov);
  const float scale = z == 0 ? SCALE_Q : 1.0f;
  const int t = threadIdx.x;
#pragma unroll
  for (int i = 0; i < 16; ++i) {
    int f = t + i * 256;
    T[f >> 6][f & 63] = w[(h * 1024 + d0 + (f >> 6)) * 64 + (f & 63)];
  }
  __syncthreads();
#pragma unroll
  for (int i = 0; i < 16; ++i) {
    int g = t + i * 256;
    o[(h * 64 + (g >> 6)) * 1024 + d0 + (g & 63)] = f2bf(T[g & 63][g >> 6] * scale);
  }
}

// Wo[k][n] f32 -> WoT[n][k] bf16 (LDS-tiled transpose)
__global__ __launch_bounds__(256) void k_convWo_t(const float* __restrict__ w, u16* __restrict__ o) {
  __shared__ float T[64][65];
  const int n0 = blockIdx.x * 64, c0 = blockIdx.y * 64;
  const int t = threadIdx.x;
#pragma unroll
  for (int i = 0; i < 16; ++i) {
    int f = t + i * 256;
    T[f >> 6][f & 63] = w[(c0 + (f >> 6)) * 1024 + n0 + (f & 63)];
  }
  __syncthreads();
#pragma unroll
  for (int i = 0; i < 16; ++i) {
    int g = t + i * 256;
    o[(n0 + (g >> 6)) * 1024 + c0 + (g & 63)] = f2bf(T[g & 63][g >> 6]);
  }
}

// ---------- fused QKV projection GEMM, counted-vmcnt 2-buffer pipeline ----------
__global__ __launch_bounds__(256) void k_gemm3(
    const u16* __restrict__ Aq, const u16* __restrict__ Ak, const u16* __restrict__ Av,
    const u16* __restrict__ Bq, const u16* __restrict__ Bk, const u16* __restrict__ Bv,
    const float* __restrict__ bqp, const float* __restrict__ bkp, const float* __restrict__ bvp,
    u16* __restrict__ oq, u16* __restrict__ ok, u16* __restrict__ ov) {
  constexpr int Kd = 1024, Nd = 1024;
  __shared__ alignas(16) u16 As[2][128 * 64];
  __shared__ alignas(16) u16 Bs[2][128 * 64];
  const int z = blockIdx.z;
  const u16* A = z == 0 ? Aq : (z == 1 ? Ak : Av);
  const u16* Bt = z == 0 ? Bq : (z == 1 ? Bk : Bv);
  const float* bias = z == 0 ? bqp : (z == 1 ? bkp : bvp);

  const int t = threadIdx.x;
  const int lane = t & 63;
  const int w = t >> 6;
  const int wm = w >> 1, wn = w & 1;
  const int lr = lane & 15, lg = lane >> 4;
  const long bm = blockIdx.x * 128, bn = blockIdx.y * 128;
  const int r8 = lane >> 3, c8 = lane & 7;
  const int chunk = c8 ^ r8;          // pre-swizzled source chunk (row&7 == r8)

  f32x4 acc[4][4] = {};
  const u16* Ap = A + (bm + w * 8 + r8) * (long)Kd + chunk * 8;
  const u16* Bp = Bt + (bn + w * 8 + r8) * (long)Kd + chunk * 8;

  auto GSTAGE = [&](u16* Asb, u16* Bsb, int kt) {
#pragma unroll
    for (int p = 0; p < 4; ++p) {
      gl16(Ap + (long)p * 32 * Kd + kt, Asb + (p * 32 + w * 8) * 64);
      gl16(Bp + (long)p * 32 * Kd + kt, Bsb + (p * 32 + w * 8) * 64);
    }
  };
  auto GCOMP = [&](const u16* Asb, const u16* Bsb) {
#pragma unroll
    for (int ks = 0; ks < 2; ++ks) {
      s8v af[4], bf[4];
#pragma unroll
      for (int i = 0; i < 4; ++i) {
        int arow = wm * 64 + i * 16 + lr;
        af[i] = *(const s8v*)(Asb + arow * 64 + (((ks * 4 + lg) ^ (arow & 7)) * 8));
        int brow = wn * 64 + i * 16 + lr;
        bf[i] = *(const s8v*)(Bsb + brow * 64 + (((ks * 4 + lg) ^ (brow & 7)) * 8));
      }
#pragma unroll
      for (int i = 0; i < 4; ++i)
#pragma unroll
        for (int j = 0; j < 4; ++j)
          acc[i][j] = __builtin_amdgcn_mfma_f32_16x16x32_bf16(af[i], bf[j], acc[i][j], 0, 0, 0);
    }
  };

  GSTAGE(As[0], Bs[0], 0);
  for (int kt = 0; kt < 16; ++kt) {
    BARRIER();                           // all waves done reading buf[(kt+1)&1]
    SCHEDB();
    if (kt < 15) {
      GSTAGE(As[(kt + 1) & 1], Bs[(kt + 1) & 1], (kt + 1) * 64);
      asm volatile("s_waitcnt vmcnt(8)" ::: "memory");   // tile-kt loads landed; kt+1 in flight
    } else {
      asm volatile("s_waitcnt vmcnt(0)" ::: "memory");
    }
    SCHEDB();
    BARRIER();                           // cross-wave: buf[kt&1] fully staged
    SCHEDB();
    GCOMP(As[kt & 1], Bs[kt & 1]);
  }

  const float bscale = z == 0 ? SCALE_Q : 1.0f;
  float bcol[4];
#pragma unroll
  for (int j = 0; j < 4; ++j) bcol[j] = bias[bn + wn * 64 + j * 16 + lr] * bscale;

  if (z < 2) {
    u16* C = z == 0 ? oq : ok;
#pragma unroll
    for (int i = 0; i < 4; ++i) {
      long m0 = bm + wm * 64 + i * 16 + lg * 4;
#pragma unroll
      for (int j = 0; j < 4; ++j) {
        long n = bn + wn * 64 + j * 16 + lr;
#pragma unroll
        for (int r = 0; r < 4; ++r)
          C[(m0 + r) * Nd + n] = f2bf(acc[i][j][r] + bcol[j]);
      }
    }
  } else {
    // V out, transposed vT[((b*16+h)*64+dv)][2048] with kv-axis pi-permutation
    // (bits 3<->2 of the within-16 s offset) so PV's B-frag is lane-local in k_attn.
    u16* C = ov;
    int lgp = ((lg & 1) << 1) | (lg >> 1);
#pragma unroll
    for (int i = 0; i < 4; ++i) {
      long m0 = bm + wm * 64 + i * 16 + lgp * 4;
      int b = (int)(m0 >> 11), s0 = (int)(m0 & 2047);
#pragma unroll
      for (int j = 0; j < 4; ++j) {
        int n = (int)(bn + wn * 64 + j * 16 + lr);
        int h = n >> 6, dv = n & 63;
        u32x2 cc;
        cc[0] = pk2(acc[i][j][0] + bcol[j], acc[i][j][1] + bcol[j]);
        cc[1] = pk2(acc[i][j][2] + bcol[j], acc[i][j][3] + bcol[j]);
        *(u32x2*)(C + (long)((b * 16 + h) * 64 + dv) * 2048 + s0) = cc;
      }
    }
  }
}

// ---------- output projection GEMM (bf16 in, f32 out), counted-vmcnt pipeline ----------
__global__ __launch_bounds__(256) void k_gemmo(const u16* __restrict__ A, const u16* __restrict__ Bt,
                                               const float* __restrict__ bias, float* __restrict__ C) {
  constexpr int Kd = 1024, Nd = 1024;
  __shared__ alignas(16) u16 As[2][128 * 64];
  __shared__ alignas(16) u16 Bs[2][128 * 64];
  const int t = threadIdx.x;
  const int lane = t & 63;
  const int w = t >> 6;
  const int wm = w >> 1, wn = w & 1;
  const int lr = lane & 15, lg = lane >> 4;
  const long bm = blockIdx.x * 128, bn = blockIdx.y * 128;
  const int r8 = lane >> 3, c8 = lane & 7;
  const int chunk = c8 ^ r8;

  f32x4 acc[4][4] = {};
  const u16* Ap = A + (bm + w * 8 + r8) * (long)Kd + chunk * 8;
  const u16* Bp = Bt + (bn + w * 8 + r8) * (long)Kd + chunk * 8;

  auto GSTAGE = [&](u16* Asb, u16* Bsb, int kt) {
#pragma unroll
    for (int p = 0; p < 4; ++p) {
      gl16(Ap + (long)p * 32 * Kd + kt, Asb + (p * 32 + w * 8) * 64);
      gl16(Bp + (long)p * 32 * Kd + kt, Bsb + (p * 32 + w * 8) * 64);
    }
  };
  auto GCOMP = [&](const u16* Asb, const u16* Bsb) {
#pragma unroll
    for (int ks = 0; ks < 2; ++ks) {
      s8v af[4], bf[4];
#pragma unroll
      for (int i = 0; i < 4; ++i) {
        int arow = wm * 64 + i * 16 + lr;
        af[i] = *(const s8v*)(Asb + arow * 64 + (((ks * 4 + lg) ^ (arow & 7)) * 8));
        int brow = wn * 64 + i * 16 + lr;
        bf[i] = *(const s8v*)(Bsb + brow * 64 + (((ks * 4 + lg) ^ (brow & 7)) * 8));
      }
#pragma unroll
      for (int i = 0; i < 4; ++i)
#pragma unroll
        for (int j = 0; j < 4; ++j)
          acc[i][j] = __builtin_amdgcn_mfma_f32_16x16x32_bf16(af[i], bf[j], acc[i][j], 0, 0, 0);
    }
  };

  GSTAGE(As[0], Bs[0], 0);
  for (int kt = 0; kt < 16; ++kt) {
    BARRIER();
    SCHEDB();
    if (kt < 15) {
      GSTAGE(As[(kt + 1) & 1], Bs[(kt + 1) & 1], (kt + 1) * 64);
      asm volatile("s_waitcnt vmcnt(8)" ::: "memory");
    } else {
      asm volatile("s_waitcnt vmcnt(0)" ::: "memory");
    }
    SCHEDB();
    BARRIER();
    SCHEDB();
    GCOMP(As[kt & 1], Bs[kt & 1]);
  }

  float bcol[4];
#pragma unroll
  for (int j = 0; j < 4; ++j) bcol[j] = bias[bn + wn * 64 + j * 16 + lr];
#pragma unroll
  for (int i = 0; i < 4; ++i) {
    long m0 = bm + wm * 64 + i * 16 + lg * 4;
#pragma unroll
    for (int j = 0; j < 4; ++j) {
      long n = bn + wn * 64 + j * 16 + lr;
#pragma unroll
      for (int r = 0; r < 4; ++r)
        C[(m0 + r) * Nd + n] = acc[i][j][r] + bcol[j];
    }
  }
}

// ---------- flash attention: barrier-free, LDS-free, register-double-buffered ----------
// q,k: [B,S,H*64] bf16 (q pre-scaled by L2E/8); vT: [B,H,64,S] bf16 pi-permuted.
// K/V are L2/L1-resident per (b,h) (512KB); each lane loads its MFMA fragments
// directly from global. No __syncthreads anywhere -> waves free-run and de-phase,
// so MFMA/VALU/trans pipes of a SIMD see a statistical mix instead of bursts.
__global__ __launch_bounds__(256, 2) void k_attn(const u16* __restrict__ q, const u16* __restrict__ k,
                                                 const u16* __restrict__ vT, u16* __restrict__ o) {
  const int t = threadIdx.x;
  const int lane = t & 63;
  const int wv = t >> 6;                 // 0..3
  const int l5 = lane & 31, hi = lane >> 5;

  // XCD-aware block swizzle: 8 qt-blocks of one (b,h) land on one XCD
  const int wg = blockIdx.x;                      // 0..511
  const int ob = (wg & 7) * 64 + (wg >> 3);       // bijective
  const int qt = ob & 7, h = (ob >> 3) & 15, b = ob >> 7;

  const int qrow0 = qt * 256 + wv * 64 + l5;      // q-block A row
  const u16* qpA = q + ((long)(b * 2048 + qrow0) * 1024 + h * 64);
  const u16* qpB = qpA + 32 * 1024;               // q-block B (+32 rows)
  s8v qfA[4], qfB[4];
#pragma unroll
  for (int s = 0; s < 4; ++s) {
    qfA[s] = *(const s8v*)(qpA + s * 16 + hi * 8);
    qfB[s] = *(const s8v*)(qpB + s * 16 + hi * 8);
  }

  // per-lane fragment bases (direct-global MFMA operands)
  const u16* Kl = k + (long)b * 2048 * 1024 + h * 64 + (long)l5 * 1024 + hi * 8;
  const u16* Vl = vT + (long)(b * 16 + h) * 131072 + (long)l5 * 2048 + hi * 8;

  f32x16 accA0 = {}, accA1 = {}, accB0 = {}, accB1 = {};
  float lA = 0.f, lB = 0.f;

  struct KV { s8v kf[4]; s8v vf[2][2]; };
  KV b0, b1;

  auto LOAD = [&](KV& bb, int kv0) {
#pragma unroll
    for (int s = 0; s < 4; ++s)
      bb.kf[s] = *(const s8v*)(Kl + (long)kv0 * 1024 + s * 16);   // K row kv0+l5, d-chunk (2s+hi)
#pragma unroll
    for (int d = 0; d < 2; ++d)
#pragma unroll
      for (int s2 = 0; s2 < 2; ++s2)
        bb.vf[d][s2] = *(const s8v*)(Vl + d * 65536 + kv0 + s2 * 16);  // vT row d*32+l5
  };

  auto COMPUTE = [&](const KV& bb) {
    f32x16 sA = {}, sB = {};
#pragma unroll
    for (int s = 0; s < 4; ++s) {
      sA = __builtin_amdgcn_mfma_f32_32x32x16_bf16(bb.kf[s], qfA[s], sA, 0, 0, 0);
      sB = __builtin_amdgcn_mfma_f32_32x32x16_bf16(bb.kf[s], qfB[s], sB, 0, 0, 0);
    }
    PU pA[2], pB[2];
#pragma unroll
    for (int r1 = 0; r1 < 4; ++r1) {
      float a0 = __builtin_amdgcn_exp2f(sA[4 * r1 + 0]);
      float a1 = __builtin_amdgcn_exp2f(sA[4 * r1 + 1]);
      float a2 = __builtin_amdgcn_exp2f(sA[4 * r1 + 2]);
      float a3 = __builtin_amdgcn_exp2f(sA[4 * r1 + 3]);
      lA += (a0 + a1) + (a2 + a3);
      pA[r1 >> 1].w[(r1 & 1) * 2 + 0] = pk2(a0, a1);
      pA[r1 >> 1].w[(r1 & 1) * 2 + 1] = pk2(a2, a3);
      float c0 = __builtin_amdgcn_exp2f(sB[4 * r1 + 0]);
      float c1 = __builtin_amdgcn_exp2f(sB[4 * r1 + 1]);
      float c2 = __builtin_amdgcn_exp2f(sB[4 * r1 + 2]);
      float c3 = __builtin_amdgcn_exp2f(sB[4 * r1 + 3]);
      lB += (c0 + c1) + (c2 + c3);
      pB[r1 >> 1].w[(r1 & 1) * 2 + 0] = pk2(c0, c1);
      pB[r1 >> 1].w[(r1 & 1) * 2 + 1] = pk2(c2, c3);
    }
#pragma unroll
    for (int s2 = 0; s2 < 2; ++s2) {
      accA0 = __builtin_amdgcn_mfma_f32_32x32x16_bf16(bb.vf[0][s2], pA[s2].v, accA0, 0, 0, 0);
      accA1 = __builtin_amdgcn_mfma_f32_32x32x16_bf16(bb.vf[1][s2], pA[s2].v, accA1, 0, 0, 0);
      accB0 = __builtin_amdgcn_mfma_f32_32x32x16_bf16(bb.vf[0][s2], pB[s2].v, accB0, 0, 0, 0);
      accB1 = __builtin_amdgcn_mfma_f32_32x32x16_bf16(bb.vf[1][s2], pB[s2].v, accB1, 0, 0, 0);
    }
  };

  // register double-buffered stream over 64 kv-chunks of 32 (no barriers, no LDS)
  LOAD(b0, 0);
  for (int it = 0; it < 64; it += 2) {
    LOAD(b1, (it + 1) * 32);
    COMPUTE(b0);
    if (it + 2 < 64) LOAD(b0, (it + 2) * 32);
    COMPUTE(b1);
  }

  lA += __shfl_xor(lA, 32);
  lB += __shfl_xor(lB, 32);
  float iA = 1.0f / lA, iB = 1.0f / lB;
  u16* opA = o + ((long)(b * 2048 + qrow0) * 1024 + h * 64);
  u16* opB = opA + 32 * 1024;
#pragma unroll
  for (int kb = 0; kb < 2; ++kb) {
#pragma unroll
    for (int r1 = 0; r1 < 4; ++r1) {
      u32x2 ca, cb;
      float a0 = kb ? accA1[4 * r1 + 0] : accA0[4 * r1 + 0];
      float a1 = kb ? accA1[4 * r1 + 1] : accA0[4 * r1 + 1];
      float a2 = kb ? accA1[4 * r1 + 2] : accA0[4 * r1 + 2];
      float a3 = kb ? accA1[4 * r1 + 3] : accA0[4 * r1 + 3];
      ca[0] = pk2(a0 * iA, a1 * iA);
      ca[1] = pk2(a2 * iA, a3 * iA);
      *(u32x2*)(opA + kb * 32 + r1 * 8 + hi * 4) = ca;
      float b0v = kb ? accB1[4 * r1 + 0] : accB0[4 * r1 + 0];
      float b1v = kb ? accB1[4 * r1 + 1] : accB0[4 * r1 + 1];
      float b2v = kb ? accB1[4 * r1 + 2] : accB0[4 * r1 + 2];
      float b3v = kb ? accB1[4 * r1 + 3] : accB0[4 * r1 + 3];
      cb[0] = pk2(b0v * iB, b1v * iB);
      cb[1] = pk2(b2v * iB, b3v * iB);
      *(u32x2*)(opB + kb * 32 + r1 * 8 + hi * 4) = cb;
    }
  }
}

extern "C" void kernel_launch(void* const* d_in, const int* in_sizes, int n_in,
                              void* d_out, int out_size, void* d_ws, size_t ws_size,
                              hipStream_t stream) {
  const float* Q  = (const float*)d_in[0];
  const float* K  = (const float*)d_in[1];
  const float* V  = (const float*)d_in[2];
  const float* Wq = (const float*)d_in[3];
  const float* bq = (const float*)d_in[4];
  const float* Wk = (const float*)d_in[5];
  const float* bk = (const float*)d_in[6];
  const float* Wv = (const float*)d_in[7];
  const float* bvp = (const float*)d_in[8];
  const float* Wo = (const float*)d_in[9];
  const float* bo = (const float*)d_in[10];
  float* out = (float*)d_out;

  char* ws = (char*)d_ws;
  const size_t MB16 = (size_t)8192 * 1024 * 2;   // 16 MiB (one 8192x1024 bf16)
  u16* Qb  = (u16*)(ws);
  u16* Kb  = (u16*)(ws + MB16);
  u16* Vb  = (u16*)(ws + 2 * MB16);
  u16* WqT = (u16*)(ws + 3 * MB16);
  u16* WkT = (u16*)(ws + 3 * MB16 + ((size_t)2 << 20));
  u16* WvT = (u16*)(ws + 3 * MB16 + ((size_t)4 << 20));
  u16* WoT = (u16*)(ws + 3 * MB16 + ((size_t)6 << 20));
  u16* qws = (u16*)(ws + 3 * MB16 + ((size_t)8 << 20));
  u16* kws = (u16*)(ws + 4 * MB16 + ((size_t)8 << 20));
  u16* vTs = (u16*)(ws + 5 * MB16 + ((size_t)8 << 20));
  u16* ows = Qb;   // Qb dead after projections; reuse for attention output

  k_conv3<<<dim3(8192, 3), 256, 0, stream>>>(Q, K, V, Qb, Kb, Vb);
  k_convW_t<<<dim3(16, 16, 3), 256, 0, stream>>>(Wq, Wk, Wv, WqT, WkT, WvT);
  k_convWo_t<<<dim3(16, 16), 256, 0, stream>>>(Wo, WoT);

  k_gemm3<<<dim3(64, 8, 3), 256, 0, stream>>>(Qb, Kb, Vb, WqT, WkT, WvT,
                                              bq, bk, bvp, qws, kws, vTs);

  k_attn<<<dim3(512), 256, 0, stream>>>(qws, kws, vTs, ows);

  k_gemmo<<<dim3(64, 8), 256, 0, stream>>>(ows, WoT, bo, out);
}

// Round 8
// 203.722 us; speedup vs baseline: 1.2055x; 1.2055x over previous
//
#include <hip/hip_runtime.h>
#include <hip/hip_bf16.h>
#include <stdint.h>

typedef unsigned short u16;
typedef uint32_t u32;
typedef __attribute__((ext_vector_type(4))) float f32x4;
typedef __attribute__((ext_vector_type(16))) float f32x16;
typedef __attribute__((ext_vector_type(8))) short s8v;     // 8 bf16 as shorts (4 VGPR)
typedef __attribute__((ext_vector_type(4))) unsigned short u16x4;
typedef __attribute__((ext_vector_type(2))) uint32_t u32x2;

#define SCALE_Q 0.18033688f   // (1/8) * log2(e): scores come out in log2 domain

union PU { s8v v; u32 w[4]; };

__device__ __forceinline__ u16 f2bf(float f) {
  union { float f; uint32_t u; } v; v.f = f;
  uint32_t r = v.u + 0x7fffu + ((v.u >> 16) & 1u);   // RNE, no NaN inputs
  return (u16)(r >> 16);
}

__device__ __forceinline__ u32 pk2(float lo, float hi) {
  __hip_bfloat162 h = __float22bfloat162_rn(float2{lo, hi});
  union { __hip_bfloat162 h; u32 u; } c; c.h = h; return c.u;
}

// async global->LDS, 16B per lane; LDS base is WAVE-UNIFORM (HW adds lane*16)
__device__ __forceinline__ void gl16(const void* g, void* l) {
  __builtin_amdgcn_global_load_lds((const __attribute__((address_space(1))) u32*)g,
                                   (__attribute__((address_space(3))) u32*)l, 16, 0, 0);
}

#define BARRIER()  __builtin_amdgcn_s_barrier()
#define SCHEDB()   __builtin_amdgcn_sched_barrier(0)
#define SGB(m, n)  __builtin_amdgcn_sched_group_barrier((m), (n), 0)

// ---------- activation f32->bf16 ----------
__global__ __launch_bounds__(256) void k_conv3(const float* __restrict__ a, const float* __restrict__ b,
                                               const float* __restrict__ c, u16* __restrict__ oa,
                                               u16* __restrict__ ob, u16* __restrict__ oc) {
  int which = blockIdx.y;
  const float* in = which == 0 ? a : (which == 1 ? b : c);
  u16* out = which == 0 ? oa : (which == 1 ? ob : oc);
  int i = (blockIdx.x * 256 + threadIdx.x) * 4;
  float4 v = *(const float4*)(in + i);
  u16x4 o; o[0] = f2bf(v.x); o[1] = f2bf(v.y); o[2] = f2bf(v.z); o[3] = f2bf(v.w);
  *(u16x4*)(out + i) = o;
}

// W[h][d][kk] f32 -> WT[n=h*64+kk][d] bf16 (LDS-tiled transpose)
__global__ __launch_bounds__(256) void k_convW_t(const float* __restrict__ wq, const float* __restrict__ wk,
                                                 const float* __restrict__ wv, u16* __restrict__ oq,
                                                 u16* __restrict__ ok, u16* __restrict__ ov) {
  __shared__ float T[64][65];
  const int z = blockIdx.z, h = blockIdx.y, d0 = blockIdx.x * 64;
  const float* w = z == 0 ? wq : (z == 1 ? wk : wv);
  u16* o = z == 0 ? oq : (z == 1 ? ok : ov);
  const float scale = z == 0 ? SCALE_Q : 1.0f;
  const int t = threadIdx.x;
#pragma unroll
  for (int i = 0; i < 16; ++i) {
    int f = t + i * 256;
    T[f >> 6][f & 63] = w[(h * 1024 + d0 + (f >> 6)) * 64 + (f & 63)];
  }
  __syncthreads();
#pragma unroll
  for (int i = 0; i < 16; ++i) {
    int g = t + i * 256;
    o[(h * 64 + (g >> 6)) * 1024 + d0 + (g & 63)] = f2bf(T[g & 63][g >> 6] * scale);
  }
}

// Wo[k][n] f32 -> WoT[n][k] bf16 (LDS-tiled transpose)
__global__ __launch_bounds__(256) void k_convWo_t(const float* __restrict__ w, u16* __restrict__ o) {
  __shared__ float T[64][65];
  const int n0 = blockIdx.x * 64, c0 = blockIdx.y * 64;
  const int t = threadIdx.x;
#pragma unroll
  for (int i = 0; i < 16; ++i) {
    int f = t + i * 256;
    T[f >> 6][f & 63] = w[(c0 + (f >> 6)) * 1024 + n0 + (f & 63)];
  }
  __syncthreads();
#pragma unroll
  for (int i = 0; i < 16; ++i) {
    int g = t + i * 256;
    o[(n0 + (g >> 6)) * 1024 + c0 + (g & 63)] = f2bf(T[g & 63][g >> 6]);
  }
}

// ---------- fused QKV projection GEMM, counted-vmcnt 2-buffer pipeline ----------
__global__ __launch_bounds__(256) void k_gemm3(
    const u16* __restrict__ Aq, const u16* __restrict__ Ak, const u16* __restrict__ Av,
    const u16* __restrict__ Bq, const u16* __restrict__ Bk, const u16* __restrict__ Bv,
    const float* __restrict__ bqp, const float* __restrict__ bkp, const float* __restrict__ bvp,
    u16* __restrict__ oq, u16* __restrict__ ok, u16* __restrict__ ov) {
  constexpr int Kd = 1024, Nd = 1024;
  __shared__ alignas(16) u16 As[2][128 * 64];
  __shared__ alignas(16) u16 Bs[2][128 * 64];
  const int z = blockIdx.z;
  const u16* A = z == 0 ? Aq : (z == 1 ? Ak : Av);
  const u16* Bt = z == 0 ? Bq : (z == 1 ? Bk : Bv);
  const float* bias = z == 0 ? bqp : (z == 1 ? bkp : bvp);

  const int t = threadIdx.x;
  const int lane = t & 63;
  const int w = t >> 6;
  const int wm = w >> 1, wn = w & 1;
  const int lr = lane & 15, lg = lane >> 4;
  const long bm = blockIdx.x * 128, bn = blockIdx.y * 128;
  const int r8 = lane >> 3, c8 = lane & 7;
  const int chunk = c8 ^ r8;          // pre-swizzled source chunk (row&7 == r8)

  f32x4 acc[4][4] = {};
  const u16* Ap = A + (bm + w * 8 + r8) * (long)Kd + chunk * 8;
  const u16* Bp = Bt + (bn + w * 8 + r8) * (long)Kd + chunk * 8;

  auto GSTAGE = [&](u16* Asb, u16* Bsb, int kt) {
#pragma unroll
    for (int p = 0; p < 4; ++p) {
      gl16(Ap + (long)p * 32 * Kd + kt, Asb + (p * 32 + w * 8) * 64);
      gl16(Bp + (long)p * 32 * Kd + kt, Bsb + (p * 32 + w * 8) * 64);
    }
  };
  auto GCOMP = [&](const u16* Asb, const u16* Bsb) {
#pragma unroll
    for (int ks = 0; ks < 2; ++ks) {
      s8v af[4], bf[4];
#pragma unroll
      for (int i = 0; i < 4; ++i) {
        int arow = wm * 64 + i * 16 + lr;
        af[i] = *(const s8v*)(Asb + arow * 64 + (((ks * 4 + lg) ^ (arow & 7)) * 8));
        int brow = wn * 64 + i * 16 + lr;
        bf[i] = *(const s8v*)(Bsb + brow * 64 + (((ks * 4 + lg) ^ (brow & 7)) * 8));
      }
#pragma unroll
      for (int i = 0; i < 4; ++i)
#pragma unroll
        for (int j = 0; j < 4; ++j)
          acc[i][j] = __builtin_amdgcn_mfma_f32_16x16x32_bf16(af[i], bf[j], acc[i][j], 0, 0, 0);
    }
  };

  GSTAGE(As[0], Bs[0], 0);
  for (int kt = 0; kt < 16; ++kt) {
    BARRIER();                           // all waves done reading buf[(kt+1)&1]
    SCHEDB();
    if (kt < 15) {
      GSTAGE(As[(kt + 1) & 1], Bs[(kt + 1) & 1], (kt + 1) * 64);
      asm volatile("s_waitcnt vmcnt(8)" ::: "memory");   // tile-kt loads landed; kt+1 in flight
    } else {
      asm volatile("s_waitcnt vmcnt(0)" ::: "memory");
    }
    SCHEDB();
    BARRIER();                           // cross-wave: buf[kt&1] fully staged
    SCHEDB();
    GCOMP(As[kt & 1], Bs[kt & 1]);
  }

  const float bscale = z == 0 ? SCALE_Q : 1.0f;
  float bcol[4];
#pragma unroll
  for (int j = 0; j < 4; ++j) bcol[j] = bias[bn + wn * 64 + j * 16 + lr] * bscale;

  if (z < 2) {
    u16* C = z == 0 ? oq : ok;
#pragma unroll
    for (int i = 0; i < 4; ++i) {
      long m0 = bm + wm * 64 + i * 16 + lg * 4;
#pragma unroll
      for (int j = 0; j < 4; ++j) {
        long n = bn + wn * 64 + j * 16 + lr;
#pragma unroll
        for (int r = 0; r < 4; ++r)
          C[(m0 + r) * Nd + n] = f2bf(acc[i][j][r] + bcol[j]);
      }
    }
  } else {
    // V out, transposed vT[((b*16+h)*64+dv)][2048] with kv-axis pi-permutation
    // (bits 3<->2 of the within-16 s offset) so PV's B-frag is lane-local in k_attn.
    u16* C = ov;
    int lgp = ((lg & 1) << 1) | (lg >> 1);
#pragma unroll
    for (int i = 0; i < 4; ++i) {
      long m0 = bm + wm * 64 + i * 16 + lgp * 4;
      int b = (int)(m0 >> 11), s0 = (int)(m0 & 2047);
#pragma unroll
      for (int j = 0; j < 4; ++j) {
        int n = (int)(bn + wn * 64 + j * 16 + lr);
        int h = n >> 6, dv = n & 63;
        u32x2 cc;
        cc[0] = pk2(acc[i][j][0] + bcol[j], acc[i][j][1] + bcol[j]);
        cc[1] = pk2(acc[i][j][2] + bcol[j], acc[i][j][3] + bcol[j]);
        *(u32x2*)(C + (long)((b * 16 + h) * 64 + dv) * 2048 + s0) = cc;
      }
    }
  }
}

// ---------- output projection GEMM (bf16 in, f32 out), counted-vmcnt pipeline ----------
__global__ __launch_bounds__(256) void k_gemmo(const u16* __restrict__ A, const u16* __restrict__ Bt,
                                               const float* __restrict__ bias, float* __restrict__ C) {
  constexpr int Kd = 1024, Nd = 1024;
  __shared__ alignas(16) u16 As[2][128 * 64];
  __shared__ alignas(16) u16 Bs[2][128 * 64];
  const int t = threadIdx.x;
  const int lane = t & 63;
  const int w = t >> 6;
  const int wm = w >> 1, wn = w & 1;
  const int lr = lane & 15, lg = lane >> 4;
  const long bm = blockIdx.x * 128, bn = blockIdx.y * 128;
  const int r8 = lane >> 3, c8 = lane & 7;
  const int chunk = c8 ^ r8;

  f32x4 acc[4][4] = {};
  const u16* Ap = A + (bm + w * 8 + r8) * (long)Kd + chunk * 8;
  const u16* Bp = Bt + (bn + w * 8 + r8) * (long)Kd + chunk * 8;

  auto GSTAGE = [&](u16* Asb, u16* Bsb, int kt) {
#pragma unroll
    for (int p = 0; p < 4; ++p) {
      gl16(Ap + (long)p * 32 * Kd + kt, Asb + (p * 32 + w * 8) * 64);
      gl16(Bp + (long)p * 32 * Kd + kt, Bsb + (p * 32 + w * 8) * 64);
    }
  };
  auto GCOMP = [&](const u16* Asb, const u16* Bsb) {
#pragma unroll
    for (int ks = 0; ks < 2; ++ks) {
      s8v af[4], bf[4];
#pragma unroll
      for (int i = 0; i < 4; ++i) {
        int arow = wm * 64 + i * 16 + lr;
        af[i] = *(const s8v*)(Asb + arow * 64 + (((ks * 4 + lg) ^ (arow & 7)) * 8));
        int brow = wn * 64 + i * 16 + lr;
        bf[i] = *(const s8v*)(Bsb + brow * 64 + (((ks * 4 + lg) ^ (brow & 7)) * 8));
      }
#pragma unroll
      for (int i = 0; i < 4; ++i)
#pragma unroll
        for (int j = 0; j < 4; ++j)
          acc[i][j] = __builtin_amdgcn_mfma_f32_16x16x32_bf16(af[i], bf[j], acc[i][j], 0, 0, 0);
    }
  };

  GSTAGE(As[0], Bs[0], 0);
  for (int kt = 0; kt < 16; ++kt) {
    BARRIER();
    SCHEDB();
    if (kt < 15) {
      GSTAGE(As[(kt + 1) & 1], Bs[(kt + 1) & 1], (kt + 1) * 64);
      asm volatile("s_waitcnt vmcnt(8)" ::: "memory");
    } else {
      asm volatile("s_waitcnt vmcnt(0)" ::: "memory");
    }
    SCHEDB();
    BARRIER();
    SCHEDB();
    GCOMP(As[kt & 1], Bs[kt & 1]);
  }

  float bcol[4];
#pragma unroll
  for (int j = 0; j < 4; ++j) bcol[j] = bias[bn + wn * 64 + j * 16 + lr];
#pragma unroll
  for (int i = 0; i < 4; ++i) {
    long m0 = bm + wm * 64 + i * 16 + lg * 4;
#pragma unroll
    for (int j = 0; j < 4; ++j) {
      long n = bn + wn * 64 + j * 16 + lr;
#pragma unroll
      for (int r = 0; r < 4; ++r)
        C[(m0 + r) * Nd + n] = acc[i][j][r] + bcol[j];
    }
  }
}

// ---------- flash attention: cross-tile pipelined (QK(t+1) || exp/PV(t)), KVBLK=32 ----------
// q,k: [B,S,H*64] bf16 (q pre-scaled by L2E/8); vT: [B,H,64,S] bf16 pi-permuted.
// 4 waves x 64q. Block-shared gl16 staging, 4 buffers, counted vmcnt(2), stage-after-barrier.
// Two score states (even/odd tile) so QK^T MFMAs of tile t+1 schedule against the
// exp/pack VALU of tile t — the pipes finally overlap.
__global__ __launch_bounds__(256, 2) void k_attn(const u16* __restrict__ q, const u16* __restrict__ k,
                                                 const u16* __restrict__ vT, u16* __restrict__ o) {
  __shared__ alignas(16) u16 Ks[4][32 * 64];   // 4 x 4KB, chunk ^= (row&7)
  __shared__ alignas(16) u16 Vs[4][64 * 32];   // 4 x 4KB, chunk ^= ((dv>>1)&3)
  const int t = threadIdx.x;
  const int lane = t & 63;
  const int wv = t >> 6;                 // 0..3
  const int l5 = lane & 31, hi = lane >> 5;
  const int r8 = lane >> 3, c8 = lane & 7;

  // XCD-aware block swizzle: 8 qt-blocks of one (b,h) land on one XCD
  const int wg = blockIdx.x;                      // 0..511
  const int ob = (wg & 7) * 64 + (wg >> 3);       // bijective
  const int qt = ob & 7, h = (ob >> 3) & 15, b = ob >> 7;

  const int qrow0 = qt * 256 + wv * 64 + l5;      // q-block A row
  const u16* qpA = q + ((long)(b * 2048 + qrow0) * 1024 + h * 64);
  const u16* qpB = qpA + 32 * 1024;               // q-block B (+32 rows)
  s8v qfA[4], qfB[4];
#pragma unroll
  for (int s = 0; s < 4; ++s) {
    qfA[s] = *(const s8v*)(qpA + s * 16 + hi * 8);
    qfB[s] = *(const s8v*)(qpB + s * 16 + hi * 8);
  }

  // staging sources (pre-swizzled for linear gl16 dest). Wave wv stages:
  //   K rows 8wv..8wv+7 (1 gl16), V rows 16wv..16wv+15 (1 gl16) per tile.
  const u16* Kst = k + (long)b * 2048 * 1024 + h * 64 + (long)(wv * 8 + r8) * 1024 + ((c8 ^ r8) * 8);
  const int dvS = wv * 16 + (lane >> 2);
  const int ccS = (lane & 3) ^ ((dvS >> 1) & 3);
  const u16* Vst = vT + (long)(b * 16 + h) * 131072 + (long)dvS * 2048 + ccS * 8;

  // fragment read offsets (u16 units)
  int koff[4];
#pragma unroll
  for (int s = 0; s < 4; ++s) koff[s] = l5 * 64 + (((2 * s + hi) ^ (l5 & 7)) * 8);
  int voff[2][2];
#pragma unroll
  for (int dh = 0; dh < 2; ++dh)
#pragma unroll
    for (int s2 = 0; s2 < 2; ++s2) {
      int dv = dh * 32 + l5;
      voff[dh][s2] = dv * 32 + (((2 * s2 + hi) ^ ((dv >> 1) & 3)) * 8);
    }

  f32x16 accA0 = {}, accA1 = {}, accB0 = {}, accB1 = {};
  float lA = 0.f, lB = 0.f;

  auto STAGE = [&](int buf, int kv0) {
    gl16(Kst + (long)kv0 * 1024, &Ks[buf][(wv * 8) * 64]);
    gl16(Vst + kv0,              &Vs[buf][(wv * 16) * 32]);
  };

  auto QKL = [&](const u16* Ksb, f32x16& sA, f32x16& sB) {
    s8v kf[4];
#pragma unroll
    for (int s = 0; s < 4; ++s) kf[s] = *(const s8v*)(Ksb + koff[s]);
#pragma unroll
    for (int s = 0; s < 4; ++s) {
      sA = __builtin_amdgcn_mfma_f32_32x32x16_bf16(kf[s], qfA[s], sA, 0, 0, 0);
      sB = __builtin_amdgcn_mfma_f32_32x32x16_bf16(kf[s], qfB[s], sB, 0, 0, 0);
    }
  };

  auto FIN = [&](const u16* Vsb, const f32x16& sA, const f32x16& sB) {
    PU pA[2], pB[2];
#pragma unroll
    for (int r1 = 0; r1 < 4; ++r1) {
      float a0 = __builtin_amdgcn_exp2f(sA[4 * r1 + 0]);
      float a1 = __builtin_amdgcn_exp2f(sA[4 * r1 + 1]);
      float a2 = __builtin_amdgcn_exp2f(sA[4 * r1 + 2]);
      float a3 = __builtin_amdgcn_exp2f(sA[4 * r1 + 3]);
      lA += (a0 + a1) + (a2 + a3);
      pA[r1 >> 1].w[(r1 & 1) * 2 + 0] = pk2(a0, a1);
      pA[r1 >> 1].w[(r1 & 1) * 2 + 1] = pk2(a2, a3);
      float c0 = __builtin_amdgcn_exp2f(sB[4 * r1 + 0]);
      float c1 = __builtin_amdgcn_exp2f(sB[4 * r1 + 1]);
      float c2 = __builtin_amdgcn_exp2f(sB[4 * r1 + 2]);
      float c3 = __builtin_amdgcn_exp2f(sB[4 * r1 + 3]);
      lB += (c0 + c1) + (c2 + c3);
      pB[r1 >> 1].w[(r1 & 1) * 2 + 0] = pk2(c0, c1);
      pB[r1 >> 1].w[(r1 & 1) * 2 + 1] = pk2(c2, c3);
    }
#pragma unroll
    for (int s2 = 0; s2 < 2; ++s2) {
      s8v vf0 = *(const s8v*)(Vsb + voff[0][s2]);
      s8v vf1 = *(const s8v*)(Vsb + voff[1][s2]);
      accA0 = __builtin_amdgcn_mfma_f32_32x32x16_bf16(vf0, pA[s2].v, accA0, 0, 0, 0);
      accA1 = __builtin_amdgcn_mfma_f32_32x32x16_bf16(vf1, pA[s2].v, accA1, 0, 0, 0);
      accB0 = __builtin_amdgcn_mfma_f32_32x32x16_bf16(vf0, pB[s2].v, accB0, 0, 0, 0);
      accB1 = __builtin_amdgcn_mfma_f32_32x32x16_bf16(vf1, pB[s2].v, accB1, 0, 0, 0);
    }
  };

  // mild T19 chain over the combined QK(t+1)+FIN(t) region: 8 DS, 16 MFMA, ~150 VALU
#define SGBCHAIN() do { _Pragma("unroll") \
    for (int g_ = 0; g_ < 8; ++g_) { SGB(0x100, 1); SGB(0x8, 2); SGB(0x2, 18); } } while (0)

  f32x16 sAE, sBE, sAO, sBO;

  // prologue
  STAGE(0, 0);
  STAGE(1, 32);
  asm volatile("s_waitcnt vmcnt(2)" ::: "memory");   // own tile-0 loads landed (tile-1 in flight)
  BARRIER();
  STAGE(2, 64);
  sAE = {}; sBE = {};
  QKL(Ks[0], sAE, sBE);

  for (int tt = 0; tt < 62; tt += 2) {
    // t = tt (even): QK(t+1) || FIN(t)
    asm volatile("s_waitcnt vmcnt(2) lgkmcnt(0)" ::: "memory");  // own t+1 landed; my ds_reads drained
    BARRIER();                                                   // block: tile t+1 staged everywhere
    STAGE((tt + 3) & 3, (tt + 3) * 32);                          // overwrites buf read at t-1 (safe)
    sAO = {}; sBO = {};
    QKL(Ks[(tt + 1) & 3], sAO, sBO);
    FIN(Vs[tt & 3], sAE, sBE);
    SGBCHAIN();
    // t = tt+1 (odd): QK(t+2) || FIN(t+1)
    asm volatile("s_waitcnt vmcnt(2) lgkmcnt(0)" ::: "memory");
    BARRIER();
    if (tt + 4 < 64) STAGE((tt + 4) & 3, (tt + 4) * 32);
    sAE = {}; sBE = {};
    QKL(Ks[(tt + 2) & 3], sAE, sBE);
    FIN(Vs[(tt + 1) & 3], sAO, sBO);
    SGBCHAIN();
  }
  // t = 62: QK(63) || FIN(62); then FIN(63)
  asm volatile("s_waitcnt vmcnt(0) lgkmcnt(0)" ::: "memory");
  BARRIER();
  sAO = {}; sBO = {};
  QKL(Ks[63 & 3], sAO, sBO);
  FIN(Vs[62 & 3], sAE, sBE);
  SGBCHAIN();
  FIN(Vs[63 & 3], sAO, sBO);

  lA += __shfl_xor(lA, 32);
  lB += __shfl_xor(lB, 32);
  float iA = 1.0f / lA, iB = 1.0f / lB;
  u16* opA = o + ((long)(b * 2048 + qrow0) * 1024 + h * 64);
  u16* opB = opA + 32 * 1024;
#pragma unroll
  for (int kb = 0; kb < 2; ++kb) {
#pragma unroll
    for (int r1 = 0; r1 < 4; ++r1) {
      u32x2 ca, cb;
      float a0 = kb ? accA1[4 * r1 + 0] : accA0[4 * r1 + 0];
      float a1 = kb ? accA1[4 * r1 + 1] : accA0[4 * r1 + 1];
      float a2 = kb ? accA1[4 * r1 + 2] : accA0[4 * r1 + 2];
      float a3 = kb ? accA1[4 * r1 + 3] : accA0[4 * r1 + 3];
      ca[0] = pk2(a0 * iA, a1 * iA);
      ca[1] = pk2(a2 * iA, a3 * iA);
      *(u32x2*)(opA + kb * 32 + r1 * 8 + hi * 4) = ca;
      float b0v = kb ? accB1[4 * r1 + 0] : accB0[4 * r1 + 0];
      float b1v = kb ? accB1[4 * r1 + 1] : accB0[4 * r1 + 1];
      float b2v = kb ? accB1[4 * r1 + 2] : accB0[4 * r1 + 2];
      float b3v = kb ? accB1[4 * r1 + 3] : accB0[4 * r1 + 3];
      cb[0] = pk2(b0v * iB, b1v * iB);
      cb[1] = pk2(b2v * iB, b3v * iB);
      *(u32x2*)(opB + kb * 32 + r1 * 8 + hi * 4) = cb;
    }
  }
#undef SGBCHAIN
}

extern "C" void kernel_launch(void* const* d_in, const int* in_sizes, int n_in,
                              void* d_out, int out_size, void* d_ws, size_t ws_size,
                              hipStream_t stream) {
  const float* Q  = (const float*)d_in[0];
  const float* K  = (const float*)d_in[1];
  const float* V  = (const float*)d_in[2];
  const float* Wq = (const float*)d_in[3];
  const float* bq = (const float*)d_in[4];
  const float* Wk = (const float*)d_in[5];
  const float* bk = (const float*)d_in[6];
  const float* Wv = (const float*)d_in[7];
  const float* bvp = (const float*)d_in[8];
  const float* Wo = (const float*)d_in[9];
  const float* bo = (const float*)d_in[10];
  float* out = (float*)d_out;

  char* ws = (char*)d_ws;
  const size_t MB16 = (size_t)8192 * 1024 * 2;   // 16 MiB (one 8192x1024 bf16)
  u16* Qb  = (u16*)(ws);
  u16* Kb  = (u16*)(ws + MB16);
  u16* Vb  = (u16*)(ws + 2 * MB16);
  u16* WqT = (u16*)(ws + 3 * MB16);
  u16* WkT = (u16*)(ws + 3 * MB16 + ((size_t)2 << 20));
  u16* WvT = (u16*)(ws + 3 * MB16 + ((size_t)4 << 20));
  u16* WoT = (u16*)(ws + 3 * MB16 + ((size_t)6 << 20));
  u16* qws = (u16*)(ws + 3 * MB16 + ((size_t)8 << 20));
  u16* kws = (u16*)(ws + 4 * MB16 + ((size_t)8 << 20));
  u16* vTs = (u16*)(ws + 5 * MB16 + ((size_t)8 << 20));
  u16* ows = Qb;   // Qb dead after projections; reuse for attention output

  k_conv3<<<dim3(8192, 3), 256, 0, stream>>>(Q, K, V, Qb, Kb, Vb);
  k_convW_t<<<dim3(16, 16, 3), 256, 0, stream>>>(Wq, Wk, Wv, WqT, WkT, WvT);
  k_convWo_t<<<dim3(16, 16), 256, 0, stream>>>(Wo, WoT);

  k_gemm3<<<dim3(64, 8, 3), 256, 0, stream>>>(Qb, Kb, Vb, WqT, WkT, WvT,
                                              bq, bk, bvp, qws, kws, vTs);

  k_attn<<<dim3(512), 256, 0, stream>>>(qws, kws, vTs, ows);

  k_gemmo<<<dim3(64, 8), 256, 0, stream>>>(ows, WoT, bo, out);
}